// Round 1
// baseline (39.553 us; speedup 1.0000x reference)
//
#include <hip/hip_runtime.h>
#include <hip/hip_bf16.h>

// SiameseConv: out[b,y,x,o] = sum_{i,j,c} det[b,y+i,x+j,c] * tmpl[b,i,j,c,o]
// det: [64,20,20,256] f32, tmpl: [64,4,4,256*20] f32 (last dim = [c][o]),
// out: [64,17,17,20] f32.
//
// Strategy: per-example GEMM C[289x20] = A[289x4096] x B[4096x20], K=(ij,c).
// K-split by channel chunks of 32 -> grid = 64 b x 8 chunks = 512 blocks,
// zero redundant global traffic (each block reads disjoint input slices).
// Stage bf16 slices in LDS (swizzled), 16x16x32 bf16 MFMA, atomicAdd partials.

typedef __bf16 bf16x8 __attribute__((ext_vector_type(8)));
typedef float f32x4 __attribute__((ext_vector_type(4)));

#define NB 64
#define C_TOT 256
#define CQ 32            // channels per block
#define NQ 8             // c-chunks (256/32)
#define NPOS 400         // 20*20 detection positions
#define NP 289           // 17*17 output positions
#define NO 20            // outputs per position
#define DET_LDS_BYTES (NPOS * CQ * 2)      // 25600: [400 pos][32 c] bf16
#define TMP_LDS_BYTES (16 * 32 * CQ * 2)   // 32768: [16 ij][32 o][32 c] bf16

__device__ __forceinline__ unsigned short f2bf(float f) {
  // round-to-nearest-even f32 -> bf16
  unsigned u = __builtin_bit_cast(unsigned, f);
  u += 0x7fffu + ((u >> 16) & 1u);
  return (unsigned short)(u >> 16);
}

__global__ __launch_bounds__(512, 4)
void siamese_kernel(const float* __restrict__ det,
                    const float* __restrict__ tmp,
                    float* __restrict__ out) {
  __shared__ alignas(16) char lds[DET_LDS_BYTES + TMP_LDS_BYTES];
  char* detB = lds;
  char* tmpB = lds + DET_LDS_BYTES;

  const int tid = threadIdx.x;
  const int b   = blockIdx.x >> 3;   // / NQ
  const int q   = blockIdx.x & 7;    // % NQ
  const int c0  = q * CQ;

  // ---- stage detection slice [400][32] bf16, granule-swizzled ----
  // rows are 64 B; swizzle 16B granule index g -> g ^ ((pos>>1)&3) so that
  // stride-64B reads across consecutive pos land on distinct bank quads.
  {
    const float* __restrict__ dsrc = det + (size_t)b * (NPOS * C_TOT);
    for (int it = tid; it < NPOS * CQ / 4; it += 512) {   // 3200 float4
      int pos = it >> 3;          // 8 float4 per pos
      int cg  = it & 7;
      const float4 v = *(const float4*)(dsrc + pos * C_TOT + c0 + cg * 4);
      unsigned long long pk =
          (unsigned long long)f2bf(v.x) |
          ((unsigned long long)f2bf(v.y) << 16) |
          ((unsigned long long)f2bf(v.z) << 32) |
          ((unsigned long long)f2bf(v.w) << 48);
      int byte = pos * 64 + (((cg >> 1) ^ ((pos >> 1) & 3)) << 4) + (cg & 1) * 8;
      *(unsigned long long*)(detB + byte) = pk;
    }
  }

  // ---- zero template pad rows (o in [20,32)) -> N-tile 1 cols read zeros ----
  {
    for (int z = tid; z < 16 * 12 * 4; z += 512) {   // 768 x 16B
      int rr = z >> 2;
      int ij = rr / 12;
      int o  = 20 + (rr % 12);
      int byte = (ij * 32 + o) * 64 + (z & 3) * 16;
      *(uint4*)(tmpB + byte) = make_uint4(0u, 0u, 0u, 0u);
    }
  }

  // ---- stage template slice transposed to [ij][o][c_local] bf16, swizzled ----
  // global layout is [ij][c][o] (o fastest); thread grabs 8 consecutive c at
  // fixed (ij,o) via 8 stride-80B loads (region is compact -> cache-friendly),
  // writes one 16B granule.
  {
    const float* __restrict__ tsrc = tmp + (size_t)b * (16 * C_TOT * NO);
    for (int it = tid; it < 16 * NO * (CQ / 8); it += 512) {   // 1280
      int ij = it / 80;
      int r  = it % 80;
      int o  = r >> 2;
      int cg = r & 3;            // which octet of c
      const float* src = tsrc + ij * (C_TOT * NO) + (c0 + cg * 8) * NO + o;
      unsigned short s[8];
      #pragma unroll
      for (int e = 0; e < 8; ++e) s[e] = f2bf(src[e * NO]);
      uint4 w;
      w.x = (unsigned)s[0] | ((unsigned)s[1] << 16);
      w.y = (unsigned)s[2] | ((unsigned)s[3] << 16);
      w.z = (unsigned)s[4] | ((unsigned)s[5] << 16);
      w.w = (unsigned)s[6] | ((unsigned)s[7] << 16);
      int row  = ij * 32 + o;
      int byte = row * 64 + (((cg ^ ((o >> 1) & 3)) << 4));
      *(uint4*)(tmpB + byte) = w;
    }
  }

  __syncthreads();

  // ---- compute: 19 M-tiles x 2 N-tiles over 8 waves, 16 K-steps of 32 ----
  const int w    = tid >> 6;
  const int lane = tid & 63;
  const int lo   = lane & 15;
  const int hi   = lane >> 4;
  const int nm   = (w < 3) ? 3 : 2;   // waves 0-2 own 3 M-tiles, rest own 2

  int posb[3];
  #pragma unroll
  for (int mi = 0; mi < 3; ++mi) {
    int m = w + mi * 8;                // M-tile index (w, w+8, w+16)
    int p = m * 16 + lo;               // A-row for this lane
    if (p > NP - 1) p = NP - 1;        // clamp pad rows (discarded at store)
    posb[mi] = (p / 17) * 20 + (p % 17);
  }

  f32x4 acc[3][2] = {};

  const int o0   = lo;                 // N-tile 0 col
  const int o1   = 16 + lo;            // N-tile 1 col (>=20 reads zeros)
  const int bad0 = (0 * 32 + o0) * 64 + ((hi ^ ((o0 >> 1) & 3)) << 4);
  const int bad1 = (0 * 32 + o1) * 64 + ((hi ^ ((o1 >> 1) & 3)) << 4);

  for (int ij = 0; ij < 16; ++ij) {
    const int i  = ij >> 2, j = ij & 3;
    const int sh = i * 20 + j;

    bf16x8 bf0 = *(const bf16x8*)(tmpB + bad0 + ij * (32 * 64));
    bf16x8 bf1 = *(const bf16x8*)(tmpB + bad1 + ij * (32 * 64));

    bf16x8 a[3];
    #pragma unroll
    for (int mi = 0; mi < 3; ++mi) {
      if (mi < nm) {
        int pos  = posb[mi] + sh;
        int byte = pos * 64 + ((hi ^ ((pos >> 1) & 3)) << 4);
        a[mi] = *(const bf16x8*)(detB + byte);
      }
    }
    #pragma unroll
    for (int mi = 0; mi < 3; ++mi) {
      if (mi < nm) {
        acc[mi][0] = __builtin_amdgcn_mfma_f32_16x16x32_bf16(a[mi], bf0, acc[mi][0], 0, 0, 0);
        acc[mi][1] = __builtin_amdgcn_mfma_f32_16x16x32_bf16(a[mi], bf1, acc[mi][1], 0, 0, 0);
      }
    }
  }

  // ---- accumulate partials to global (d_out pre-zeroed each launch) ----
  float* __restrict__ ob = out + (size_t)b * (NP * NO);
  #pragma unroll
  for (int mi = 0; mi < 3; ++mi) {
    if (mi < nm) {
      int m = w + mi * 8;
      #pragma unroll
      for (int n = 0; n < 2; ++n) {
        int o = n * 16 + lo;
        if (o < NO) {
          #pragma unroll
          for (int v = 0; v < 4; ++v) {
            int p = m * 16 + hi * 4 + v;   // C/D: row=(lane>>4)*4+reg, col=lane&15
            if (p < NP) atomicAdd(ob + p * NO + o, acc[mi][n][v]);
          }
        }
      }
    }
  }
}

extern "C" void kernel_launch(void* const* d_in, const int* in_sizes, int n_in,
                              void* d_out, int out_size, void* d_ws, size_t ws_size,
                              hipStream_t stream) {
  (void)in_sizes; (void)n_in; (void)d_ws; (void)ws_size;
  const float* det = (const float*)d_in[0];
  const float* tmp = (const float*)d_in[1];
  float* out = (float*)d_out;
  // zero output each launch (deterministic; atomics then accumulate partials)
  hipMemsetAsync(d_out, 0, (size_t)out_size * sizeof(float), stream);
  siamese_kernel<<<dim3(NB * NQ), dim3(512), 0, stream>>>(det, tmp, out);
}